// Round 4
// baseline (249.941 us; speedup 1.0000x reference)
//
#include <hip/hip_runtime.h>
#include <hip/hip_bf16.h>
#include <math.h>

#define HW 16384
#define NC 64
#define NB 16
#define BPB 32                  // blocks per batch -> grid 512
#define KPB (HW / BPB)          // 512 k per block
#define KPW (KPB / 4)           // 128 k per wave
#define NIT (KPW / 32)          // 4 MFMA k-steps per wave

// ws layout (floats):
//   [0,1024)    S_v    [1024,2048) S_t    [2048,3072) U_t
//   [3072,4096) gw
//   [4096, 4096+npart*65536)  J_raw partial copies (npart x NB x 64 x 64)

typedef __attribute__((ext_vector_type(8))) short bf16x8;
typedef __attribute__((ext_vector_type(4))) float f32x4;

__device__ inline short bfs(float x) {
  union { __hip_bfloat16 h; short s; } u;
  u.h = __float2bfloat16(x);    // RNE; compiler pairs into v_cvt_pk_bf16_f32
  return u.s;
}

__device__ inline float wave_reduce_sum(float v) {
#pragma unroll
  for (int o = 32; o > 0; o >>= 1) v += __shfl_down(v, o, 64);
  return v;
}

__global__ __launch_bounds__(256, 2) void joint_nolds(const float* __restrict__ vis,
                                                      const float* __restrict__ text,
                                                      float* __restrict__ ws,
                                                      int jmask) {
  const int b  = blockIdx.x / BPB;
  const int kc = blockIdx.x % BPB;
  const int t  = threadIdx.x;
  const int w  = t >> 6;
  const int l  = t & 63;

  // fragment addressing: lane l covers row (l&15)+16*fi, k = (l>>4)*8 + [0..8)
  const int k0 = kc * KPB + w * KPW + ((l >> 4) * 8);
  const float* Ap = vis  + ((size_t)b * NC + (l & 15)) * HW + k0;
  const float* Bp = text + ((size_t)b * NC + (l & 15)) * HW + k0;

  f32x4 acc[4][4];
#pragma unroll
  for (int i = 0; i < 4; ++i)
#pragma unroll
    for (int j = 0; j < 4; ++j) acc[i][j] = (f32x4){0.f, 0.f, 0.f, 0.f};

  float sv[4] = {0.f, 0.f, 0.f, 0.f};
  float st[4] = {0.f, 0.f, 0.f, 0.f};
  float ut[4] = {0.f, 0.f, 0.f, 0.f};

  // prefetch registers: 4 frags x 8 fp32 for A and B
  f32x4 pa[4][2], pb[4][2];
#pragma unroll
  for (int fi = 0; fi < 4; ++fi) {
    const f32x4* ap = (const f32x4*)(Ap + (size_t)fi * 16 * HW);
    const f32x4* bp = (const f32x4*)(Bp + (size_t)fi * 16 * HW);
    pa[fi][0] = ap[0]; pa[fi][1] = ap[1];
    pb[fi][0] = bp[0]; pb[fi][1] = bp[1];
  }

#pragma unroll
  for (int it = 0; it < NIT; ++it) {
    bf16x8 fa[4], fb[4];
#pragma unroll
    for (int fi = 0; fi < 4; ++fi) {
      f32x4 a0 = pa[fi][0], a1 = pa[fi][1];
      f32x4 b0 = pb[fi][0], b1 = pb[fi][1];
      float ea[8], eb[8];
#pragma unroll
      for (int j = 0; j < 4; ++j) {
        ea[j] = __expf(a0[j]); ea[4 + j] = __expf(a1[j]);
        eb[j] = __expf(b0[j]); eb[4 + j] = __expf(b1[j]);
      }
      sv[fi] += ((ea[0] + ea[1]) + (ea[2] + ea[3])) + ((ea[4] + ea[5]) + (ea[6] + ea[7]));
      st[fi] += ((eb[0] + eb[1]) + (eb[2] + eb[3])) + ((eb[4] + eb[5]) + (eb[6] + eb[7]));
      ut[fi] += ((eb[0] * b0[0] + eb[1] * b0[1]) + (eb[2] * b0[2] + eb[3] * b0[3]))
              + ((eb[4] * b1[0] + eb[5] * b1[1]) + (eb[6] * b1[2] + eb[7] * b1[3]));
#pragma unroll
      for (int j = 0; j < 8; ++j) { fa[fi][j] = bfs(ea[j]); fb[fi][j] = bfs(eb[j]); }
    }

    // prefetch next k-step (WAR on pa/pb after conversion; overlaps MFMA)
    if (it + 1 < NIT) {
#pragma unroll
      for (int fi = 0; fi < 4; ++fi) {
        const f32x4* ap = (const f32x4*)(Ap + (size_t)fi * 16 * HW + (it + 1) * 32);
        const f32x4* bp = (const f32x4*)(Bp + (size_t)fi * 16 * HW + (it + 1) * 32);
        pa[fi][0] = ap[0]; pa[fi][1] = ap[1];
        pb[fi][0] = bp[0]; pb[fi][1] = bp[1];
      }
    }

#pragma unroll
    for (int fi = 0; fi < 4; ++fi)
#pragma unroll
      for (int fj = 0; fj < 4; ++fj)
        acc[fi][fj] = __builtin_amdgcn_mfma_f32_16x16x32_bf16(fa[fi], fb[fj], acc[fi][fj], 0, 0, 0);
  }

  // ---- epilogue: block-level LDS reduce, then global atomics ----
  __shared__ float red[4096 + 192];
  for (int i = t; i < 4096 + 192; i += 256) red[i] = 0.f;
  __syncthreads();

  // J: C/D layout col = l&15, row = (l>>4)*4 + reg (verified R2)
#pragma unroll
  for (int fi = 0; fi < 4; ++fi)
#pragma unroll
    for (int fj = 0; fj < 4; ++fj)
#pragma unroll
      for (int r = 0; r < 4; ++r)
        atomicAdd(&red[(16 * fi + (l >> 4) * 4 + r) * 64 + 16 * fj + (l & 15)],
                  acc[fi][fj][r]);

  // stats: lanes l, l+16, l+32, l+48 hold same-row partials over disjoint k
#pragma unroll
  for (int fi = 0; fi < 4; ++fi) {
    sv[fi] += __shfl_xor(sv[fi], 16, 64); sv[fi] += __shfl_xor(sv[fi], 32, 64);
    st[fi] += __shfl_xor(st[fi], 16, 64); st[fi] += __shfl_xor(st[fi], 32, 64);
    ut[fi] += __shfl_xor(ut[fi], 16, 64); ut[fi] += __shfl_xor(ut[fi], 32, 64);
  }
  if (l < 16) {
#pragma unroll
    for (int fi = 0; fi < 4; ++fi) {
      atomicAdd(&red[4096 +       16 * fi + l], sv[fi]);
      atomicAdd(&red[4096 +  64 + 16 * fi + l], st[fi]);
      atomicAdd(&red[4096 + 128 + 16 * fi + l], ut[fi]);
    }
  }
  __syncthreads();

  float* J = ws + 4096 + ((size_t)((kc & jmask) * NB + b)) * 4096;
#pragma unroll
  for (int j = 0; j < 16; ++j)
    atomicAdd(&J[t * 16 + j], red[t * 16 + j]);

  if (t < 192) {
    int stat = t >> 6, r = t & 63;
    atomicAdd(&ws[stat * 1024 + b * 64 + r], red[4096 + t]);
  }
}

__global__ __launch_bounds__(256) void mi_gw_kernel(const float* __restrict__ ws,
                                                    float* __restrict__ gw,
                                                    int npart) {
  const int b = blockIdx.x, t = threadIdx.x;
  __shared__ float sSv[64], sSt[64];
  if (t < 64) sSv[t] = ws[b * 64 + t];
  else if (t < 128) sSt[t - 64] = ws[1024 + b * 64 + (t - 64)];
  __syncthreads();

  // thread t owns J elements [16t, 16t+16): row c = t>>2, cols d = (t&3)*16 + [0,16)
  f32x4 jr0 = {0,0,0,0}, jr1 = {0,0,0,0}, jr2 = {0,0,0,0}, jr3 = {0,0,0,0};
  const float* base = ws + 4096 + (size_t)b * 4096 + t * 16;
  for (int p = 0; p < npart; ++p) {
    const f32x4* cp = (const f32x4*)(base + (size_t)p * (NB * 4096));
    jr0 += cp[0]; jr1 += cp[1]; jr2 += cp[2]; jr3 += cp[3];
  }

  const float HW2 = (float)HW * (float)HW;
  const float fv = HW2 / sSv[t >> 2];
  const int d0 = (t & 3) * 16;
  float part = 0.f;
#pragma unroll
  for (int j = 0; j < 16; ++j) {
    float jv = (j < 4) ? jr0[j] : (j < 8) ? jr1[j - 4] : (j < 12) ? jr2[j - 8] : jr3[j - 12];
    float q = jv * (fv / sSt[d0 + j]);
    part += q * __logf(q + 1e-9f);
  }
  part = wave_reduce_sum(part);
  __shared__ float sh[4];
  __shared__ float mi_sh;
  int wid = t >> 6, lane = t & 63;
  if (lane == 0) sh[wid] = part;
  __syncthreads();
  if (t == 0) mi_sh = ((sh[0] + sh[1]) + (sh[2] + sh[3])) / HW2;
  __syncthreads();
  if (t < 64) {
    float S = sSt[t];
    float U = ws[2048 + b * 64 + t];
    float ent = __logf(S) - U / S;               // text spatial entropy
    float z = 1.0f - ent + 0.5f * mi_sh;
    gw[b * 64 + t] = 1.0f / (1.0f + __expf(-z));
  }
}

__global__ __launch_bounds__(256) void enhance_kernel(const float4* __restrict__ vis,
                                                      const float4* __restrict__ text,
                                                      const float* __restrict__ gw,
                                                      float4* __restrict__ out) {
  const size_t total4 = (size_t)NB * NC * HW / 4;   // 4194304
  for (size_t i = (size_t)blockIdx.x * 256 + threadIdx.x; i < total4;
       i += (size_t)gridDim.x * 256) {
    float4 v = vis[i];
    float4 t = text[i];
    float g = gw[i >> 12];              // 4096 float4 per (b,c) row
    out[i] = make_float4(v.x + g * t.x, v.y + g * t.y,
                         v.z + g * t.z, v.w + g * t.w);
  }
}

extern "C" void kernel_launch(void* const* d_in, const int* in_sizes, int n_in,
                              void* d_out, int out_size, void* d_ws, size_t ws_size,
                              hipStream_t stream) {
  const float* vis  = (const float*)d_in[0];
  const float* text = (const float*)d_in[1];
  float* out = (float*)d_out;
  float* ws  = (float*)d_ws;
  float* gw  = ws + 3072;

  // npart J copies chosen deterministically from scratch size
  size_t ws_floats = ws_size / sizeof(float);
  int npart = 1;
  if      (ws_floats >= 4096 + 8 * 65536) npart = 8;
  else if (ws_floats >= 4096 + 4 * 65536) npart = 4;
  else if (ws_floats >= 4096 + 2 * 65536) npart = 2;

  hipMemsetAsync(ws, 0, (4096 + (size_t)npart * 65536) * sizeof(float), stream);

  joint_nolds<<<NB * BPB, 256, 0, stream>>>(vis, text, ws, npart - 1);
  mi_gw_kernel<<<NB, 256, 0, stream>>>(ws, gw, npart);
  enhance_kernel<<<2048, 256, 0, stream>>>((const float4*)vis, (const float4*)text,
                                           gw, (float4*)out);
}

// Round 5
// 71.862 us; speedup vs baseline: 3.4781x; 3.4781x over previous
//
#include <hip/hip_runtime.h>
#include <hip/hip_bf16.h>
#include <math.h>

#define HW 16384
#define NC 64
#define NB 16
#define CH 32               // k-chunks per batch -> grid 512 (2 blocks/CU)
#define KPB (HW / CH)       // 512 k per block
#define KPW (KPB / 4)       // 128 k per wave
#define NST (KPW / 32)      // 4 stages of KC=32 per wave

// ws layout (floats):
//   [0,1024)    S_v    [1024,2048) S_t    [2048,3072) U_t
//   [3072,4096) gw
//   [4096, 4096+npart*65536)  J_raw partial copies (npart x NB x 64 x 64)

typedef __attribute__((ext_vector_type(8))) short bf16x8;
typedef __attribute__((ext_vector_type(4))) float f32x4;

__device__ inline short bfs(float x) {
  union { __hip_bfloat16 h; short s; } u;
  u.h = __float2bfloat16(x);            // RNE
  return u.s;
}

__device__ inline float wave_reduce_sum(float v) {
#pragma unroll
  for (int o = 32; o > 0; o >>= 1) v += __shfl_down(v, o, 64);
  return v;
}

#if __has_builtin(__builtin_amdgcn_global_load_lds)
#define HAS_GLDS 1
// async global->LDS, 16B/lane, dest = wave-uniform base + lane*16
__device__ inline void gload16(const float* g, float* l) {
  __builtin_amdgcn_global_load_lds(
      (const __attribute__((address_space(1))) void*)g,
      (__attribute__((address_space(3))) void*)l, 16, 0, 0);
}
#else
#define HAS_GLDS 0
__device__ inline void gload16(const float* g, float* l) {
  *(f32x4*)(l + (threadIdx.x & 63) * 4) = *(const f32x4*)g;
}
#endif

// Wave-private tile: [64 rows][32 k] f32, row-major (row stride 128B).
// Content is k-slot swizzled: storage slot s' holds logical slot s = s'^(row&7).
// Achieved by pre-swizzling the GLOBAL source address (rule: swizzle both
// sides or neither with global_load_lds).

__global__ __launch_bounds__(256) void joint_async(const float* __restrict__ vis,
                                                   const float* __restrict__ text,
                                                   float* __restrict__ ws,
                                                   int jmask) {
  const int b = blockIdx.x / CH;
  const int chunk = blockIdx.x % CH;
  const int t = threadIdx.x;
  const int w = t >> 6;
  const int l = t & 63;

  __shared__ float smem[4 * 4288];      // 68608 B: [0,16384) tiles, then reduce buf

  float* V = smem + w * 4096;           // wave-private vis tile (2048 f32)
  float* T = V + 2048;                  // wave-private text tile

  const int kw = chunk * KPB + w * KPW;
  const int srow = l >> 3;                        // source row-in-group 0..7
  const int scol = ((l & 7) ^ srow) << 2;         // pre-swizzled float col
  const float* vg = vis  + ((size_t)b * NC + srow) * HW + kw + scol;
  const float* tg = text + ((size_t)b * NC + srow) * HW + kw + scol;

  // prologue: issue stage 0 (8 rows x 8 instrs per tensor, 1KB LDS each)
#pragma unroll
  for (int i = 0; i < 8; ++i) {
    gload16(vg + (size_t)i * 8 * HW, V + i * 256);
    gload16(tg + (size_t)i * 8 * HW, T + i * 256);
  }

  // fragment read offsets (A: lane m = l&15, k = (l>>4)*8 + [0,8))
  const int xorv = l & 7;                          // = row&7 for all frag rows
  const int s0 = (l >> 4) << 1;                    // logical 4-float slot
  const int offF0 = (l & 15) * 32 + ((s0 ^ xorv) << 2);
  const int offF1 = (l & 15) * 32 + (((s0 | 1) ^ xorv) << 2);

  f32x4 acc[4][4];
#pragma unroll
  for (int i = 0; i < 4; ++i)
#pragma unroll
    for (int j = 0; j < 4; ++j) acc[i][j] = (f32x4){0.f, 0.f, 0.f, 0.f};
  float sv[4] = {0.f, 0.f, 0.f, 0.f};
  float st[4] = {0.f, 0.f, 0.f, 0.f};
  float ut[4] = {0.f, 0.f, 0.f, 0.f};

  for (int it = 0; it < NST; ++it) {
    asm volatile("s_waitcnt vmcnt(0)" ::: "memory");   // stage it resident in LDS

    // read all f32 fragments for this stage (16 x ds_read_b128, conflict-free)
    f32x4 av0[4], av1[4], bv0[4], bv1[4];
#pragma unroll
    for (int f = 0; f < 4; ++f) {
      av0[f] = *(const f32x4*)(V + f * 512 + offF0);
      av1[f] = *(const f32x4*)(V + f * 512 + offF1);
      bv0[f] = *(const f32x4*)(T + f * 512 + offF0);
      bv1[f] = *(const f32x4*)(T + f * 512 + offF1);
    }
    asm volatile("s_waitcnt lgkmcnt(0)" ::: "memory"); // frag data now in VGPRs

    // issue next stage into the same LDS buffer (safe: reads complete)
    if (it + 1 < NST) {
#pragma unroll
      for (int i = 0; i < 8; ++i) {
        gload16(vg + (size_t)i * 8 * HW + (it + 1) * 32, V + i * 256);
        gload16(tg + (size_t)i * 8 * HW + (it + 1) * 32, T + i * 256);
      }
    }

    // exp + stats + cvt (overlaps the in-flight async loads)
    bf16x8 fa[4], fb[4];
#pragma unroll
    for (int f = 0; f < 4; ++f) {
      float e0 = __expf(av0[f][0]), e1 = __expf(av0[f][1]),
            e2 = __expf(av0[f][2]), e3 = __expf(av0[f][3]),
            e4 = __expf(av1[f][0]), e5 = __expf(av1[f][1]),
            e6 = __expf(av1[f][2]), e7 = __expf(av1[f][3]);
      sv[f] += ((e0 + e1) + (e2 + e3)) + ((e4 + e5) + (e6 + e7));
      fa[f][0] = bfs(e0); fa[f][1] = bfs(e1); fa[f][2] = bfs(e2); fa[f][3] = bfs(e3);
      fa[f][4] = bfs(e4); fa[f][5] = bfs(e5); fa[f][6] = bfs(e6); fa[f][7] = bfs(e7);
    }
#pragma unroll
    for (int f = 0; f < 4; ++f) {
      float e0 = __expf(bv0[f][0]), e1 = __expf(bv0[f][1]),
            e2 = __expf(bv0[f][2]), e3 = __expf(bv0[f][3]),
            e4 = __expf(bv1[f][0]), e5 = __expf(bv1[f][1]),
            e6 = __expf(bv1[f][2]), e7 = __expf(bv1[f][3]);
      st[f] += ((e0 + e1) + (e2 + e3)) + ((e4 + e5) + (e6 + e7));
      ut[f] += ((e0 * bv0[f][0] + e1 * bv0[f][1]) + (e2 * bv0[f][2] + e3 * bv0[f][3]))
             + ((e4 * bv1[f][0] + e5 * bv1[f][1]) + (e6 * bv1[f][2] + e7 * bv1[f][3]));
      fb[f][0] = bfs(e0); fb[f][1] = bfs(e1); fb[f][2] = bfs(e2); fb[f][3] = bfs(e3);
      fb[f][4] = bfs(e4); fb[f][5] = bfs(e5); fb[f][6] = bfs(e6); fb[f][7] = bfs(e7);
    }

#pragma unroll
    for (int fi = 0; fi < 4; ++fi)
#pragma unroll
      for (int fj = 0; fj < 4; ++fj)
        acc[fi][fj] = __builtin_amdgcn_mfma_f32_16x16x32_bf16(fa[fi], fb[fj],
                                                              acc[fi][fj], 0, 0, 0);
  }

  // ---- stats: lanes l, l+16, l+32, l+48 hold same rows, disjoint k ----
#pragma unroll
  for (int f = 0; f < 4; ++f) {
    sv[f] += __shfl_xor(sv[f], 16, 64); sv[f] += __shfl_xor(sv[f], 32, 64);
    st[f] += __shfl_xor(st[f], 16, 64); st[f] += __shfl_xor(st[f], 32, 64);
    ut[f] += __shfl_xor(ut[f], 16, 64); ut[f] += __shfl_xor(ut[f], 32, 64);
  }

  __syncthreads();   // all waves done with tiles; reuse smem as [4][4288] reduce buf

  float* red = smem + w * 4288;
  const int m16 = l & 15, q4 = (l >> 4) * 4;
  // C/D layout: col = l&15, row = (l>>4)*4 + reg (verified R2/R4)
#pragma unroll
  for (int fi = 0; fi < 4; ++fi)
#pragma unroll
    for (int fj = 0; fj < 4; ++fj)
#pragma unroll
      for (int r = 0; r < 4; ++r)
        red[(16 * fi + q4 + r) * 64 + 16 * fj + m16] = acc[fi][fj][r];
  if (l < 16) {
#pragma unroll
    for (int fi = 0; fi < 4; ++fi) {
      red[4096 +   0 + 16 * fi + l] = sv[fi];
      red[4096 +  64 + 16 * fi + l] = st[fi];
      red[4096 + 128 + 16 * fi + l] = ut[fi];
    }
  }
  __syncthreads();

  float* Jp = ws + 4096 + (size_t)((chunk & jmask) * NB + b) * 4096;
  for (int i = t; i < 4096; i += 256) {
    float s = (smem[i] + smem[4288 + i]) + (smem[2 * 4288 + i] + smem[3 * 4288 + i]);
    atomicAdd(&Jp[i], s);
  }
  if (t < 192) {
    float s = (smem[4096 + t] + smem[4288 + 4096 + t])
            + (smem[2 * 4288 + 4096 + t] + smem[3 * 4288 + 4096 + t]);
    atomicAdd(&ws[(t >> 6) * 1024 + b * 64 + (t & 63)], s);
  }
}

__global__ __launch_bounds__(256) void mi_gw_kernel(const float* __restrict__ ws,
                                                    float* __restrict__ gw,
                                                    int npart) {
  const int b = blockIdx.x, t = threadIdx.x;
  __shared__ float sSv[64], sSt[64];
  if (t < 64) sSv[t] = ws[b * 64 + t];
  else if (t < 128) sSt[t - 64] = ws[1024 + b * 64 + (t - 64)];
  __syncthreads();

  // thread t owns J elements [16t,16t+16): row c = t>>2, cols d = (t&3)*16+[0,16)
  f32x4 jr0 = {0,0,0,0}, jr1 = {0,0,0,0}, jr2 = {0,0,0,0}, jr3 = {0,0,0,0};
  const float* base = ws + 4096 + (size_t)b * 4096 + t * 16;
  for (int p = 0; p < npart; ++p) {
    const f32x4* cp = (const f32x4*)(base + (size_t)p * (NB * 4096));
    jr0 += cp[0]; jr1 += cp[1]; jr2 += cp[2]; jr3 += cp[3];
  }

  const float HW2 = (float)HW * (float)HW;
  const float fv = HW2 / sSv[t >> 2];
  const int d0 = (t & 3) * 16;
  float part = 0.f;
#pragma unroll
  for (int j = 0; j < 16; ++j) {
    float jv = (j < 4) ? jr0[j] : (j < 8) ? jr1[j - 4] : (j < 12) ? jr2[j - 8] : jr3[j - 12];
    float q = jv * (fv / sSt[d0 + j]);
    part += q * __logf(q + 1e-9f);
  }
  part = wave_reduce_sum(part);
  __shared__ float sh[4];
  __shared__ float mi_sh;
  int wid = t >> 6, lane = t & 63;
  if (lane == 0) sh[wid] = part;
  __syncthreads();
  if (t == 0) mi_sh = ((sh[0] + sh[1]) + (sh[2] + sh[3])) / HW2;
  __syncthreads();
  if (t < 64) {
    float S = sSt[t];
    float U = ws[2048 + b * 64 + t];
    float ent = __logf(S) - U / S;               // text spatial entropy
    float z = 1.0f - ent + 0.5f * mi_sh;
    gw[b * 64 + t] = 1.0f / (1.0f + __expf(-z));
  }
}

__global__ __launch_bounds__(256) void enhance_kernel(const float4* __restrict__ vis,
                                                      const float4* __restrict__ text,
                                                      const float* __restrict__ gw,
                                                      float4* __restrict__ out) {
  const size_t total4 = (size_t)NB * NC * HW / 4;   // 4194304
  for (size_t i = (size_t)blockIdx.x * 256 + threadIdx.x; i < total4;
       i += (size_t)gridDim.x * 256) {
    float4 v = vis[i];
    float4 t = text[i];
    float g = gw[i >> 12];              // 4096 float4 per (b,c) row
    out[i] = make_float4(v.x + g * t.x, v.y + g * t.y,
                         v.z + g * t.z, v.w + g * t.w);
  }
}

extern "C" void kernel_launch(void* const* d_in, const int* in_sizes, int n_in,
                              void* d_out, int out_size, void* d_ws, size_t ws_size,
                              hipStream_t stream) {
  const float* vis  = (const float*)d_in[0];
  const float* text = (const float*)d_in[1];
  float* out = (float*)d_out;
  float* ws  = (float*)d_ws;
  float* gw  = ws + 3072;

  // npart J partial copies, chosen deterministically from scratch size
  size_t ws_floats = ws_size / sizeof(float);
  int npart = 1;
  if      (ws_floats >= 4096 + 4 * 65536) npart = 4;
  else if (ws_floats >= 4096 + 2 * 65536) npart = 2;

  hipMemsetAsync(ws, 0, (4096 + (size_t)npart * 65536) * sizeof(float), stream);

  joint_async<<<NB * CH, 256, 0, stream>>>(vis, text, ws, npart - 1);
  mi_gw_kernel<<<NB, 256, 0, stream>>>(ws, gw, npart);
  enhance_kernel<<<2048, 256, 0, stream>>>((const float4*)vis, (const float4*)text,
                                           gw, (float4*)out);
}